// Round 2
// baseline (335.271 us; speedup 1.0000x reference)
//
#include <hip/hip_runtime.h>
#include <hip/hip_cooperative_groups.h>
#include <math.h>

#define HID   2048
#define NEXP  64
#define NTOK  16384
#define SBLK  64      // sinkhorn blocks
#define TOLF  1e-4f
#define EPSF  1e-8f

typedef _Float16 f16x8 __attribute__((ext_vector_type(8)));
typedef float    f32x4 __attribute__((ext_vector_type(4)));

// ---------------------------------------------------------------------------
// Kernel 0: split W (64x2048 fp32) into Wh + Wl*2048 (f16, same [e][k] layout).
// f16x3 trick: x@W ~= xh@Wh + (xh@Wl' + xl'@Wh)/2048, residuals exact
// (Sterbenz), net error ~2^-24 * scale -- below fp32 reassociation noise.
// 64 blocks x 256 thr x 8 elems = 131072 elems. ~2us.
// ---------------------------------------------------------------------------
__global__ __launch_bounds__(256) void convert_w(const float* __restrict__ W,
                                                 _Float16* __restrict__ Wh,
                                                 _Float16* __restrict__ Wl) {
    const int i = ((int)blockIdx.x * 256 + (int)threadIdx.x) * 8;
    const float4 w0 = *(const float4*)(W + i);
    const float4 w1 = *(const float4*)(W + i + 4);
    float v[8] = {w0.x, w0.y, w0.z, w0.w, w1.x, w1.y, w1.z, w1.w};
    f16x8 h, l;
#pragma unroll
    for (int j = 0; j < 8; ++j) {
        const _Float16 hh = (_Float16)v[j];
        h[j] = hh;
        l[j] = (_Float16)((v[j] - (float)hh) * 2048.0f);
    }
    *(f16x8*)(Wh + i) = h;
    *(f16x8*)(Wl + i) = l;
}

// ---------------------------------------------------------------------------
// Kernel 1: logits via f16x3 MFMA. Grid = 256 blocks x 256 thr (4 waves).
// Wave owns 16 tokens x 64 experts. NO LDS: A-fragment of 16x16x32 f16 MFMA
// is lane(l&15)=token-row, 8 k-consecutive elems at k-block (l>>4)*8 -- the
// wave's global fp32 loads form 16 rows x 128B contiguous segments (fully
// coalesced). B-fragments read Wh/Wl f16 rows directly (512KB, L2-resident;
// each wave touches W exactly once). Old fp32 kernel was LDS-issue-bound
// (~16K ds_read_b128/CU x 12cyc ~ 82us); this is HBM-bound (~22us floor).
// C/D layout (verified, dtype-independent): col=lane&15, row=(lane>>4)*4+r.
// ---------------------------------------------------------------------------
__global__ __launch_bounds__(256) void gemm_mfma(const float* __restrict__ x,
                                                 const _Float16* __restrict__ Wh,
                                                 const _Float16* __restrict__ Wl,
                                                 float* __restrict__ L) {
    const int wave = (int)threadIdx.x >> 6;
    const int lane = (int)threadIdx.x & 63;
    const int lo = lane & 15;        // token row (A) / expert col (B,D)
    const int hi = lane >> 4;        // k-block 0..3 (A,B) / row-group (D)
    const int t0 = (int)blockIdx.x * 64 + wave * 16;

    const float*    xp  = x  + (size_t)(t0 + lo) * HID + hi * 8;
    const _Float16* bhp = Wh + (size_t)lo * HID + hi * 8;
    const _Float16* blp = Wl + (size_t)lo * HID + hi * 8;

    f32x4 acc_hh[4], acc_hl[4];
#pragma unroll
    for (int n = 0; n < 4; ++n) {
        acc_hh[n] = f32x4{0.f, 0.f, 0.f, 0.f};
        acc_hl[n] = f32x4{0.f, 0.f, 0.f, 0.f};
    }

    // 1-step-ahead prefetch registers (copy-at-top creates the distance).
    float4 a0n = *(const float4*)(xp);
    float4 a1n = *(const float4*)(xp + 4);
    f16x8 bhn[4], bln[4];
#pragma unroll
    for (int n = 0; n < 4; ++n) {
        bhn[n] = *(const f16x8*)(bhp + n * 16 * HID);
        bln[n] = *(const f16x8*)(blp + n * 16 * HID);
    }

#pragma unroll 2
    for (int s = 0; s < 64; ++s) {
        const float4 a0 = a0n, a1 = a1n;
        f16x8 bh[4], bl[4];
#pragma unroll
        for (int n = 0; n < 4; ++n) { bh[n] = bhn[n]; bl[n] = bln[n]; }

        // issue next step's loads (clamped re-read of step 63 at the tail)
        const int ko = ((s + 1 < 64) ? (s + 1) : 63) * 32;
        a0n = *(const float4*)(xp + ko);
        a1n = *(const float4*)(xp + ko + 4);
#pragma unroll
        for (int n = 0; n < 4; ++n) {
            bhn[n] = *(const f16x8*)(bhp + n * 16 * HID + ko);
            bln[n] = *(const f16x8*)(blp + n * 16 * HID + ko);
        }

        // split current A chunk: xh (RTN) + xl*2048 (residual exact)
        f16x8 ah, al;
        const float av[8] = {a0.x, a0.y, a0.z, a0.w, a1.x, a1.y, a1.z, a1.w};
#pragma unroll
        for (int j = 0; j < 8; ++j) {
            const _Float16 hh = (_Float16)av[j];
            ah[j] = hh;
            al[j] = (_Float16)((av[j] - (float)hh) * 2048.0f);
        }

        // 12 MFMA; dependent acc_hl pairs separated by 4 independent MFMAs
#pragma unroll
        for (int n = 0; n < 4; ++n)
            acc_hh[n] = __builtin_amdgcn_mfma_f32_16x16x32_f16(ah, bh[n], acc_hh[n], 0, 0, 0);
#pragma unroll
        for (int n = 0; n < 4; ++n)
            acc_hl[n] = __builtin_amdgcn_mfma_f32_16x16x32_f16(ah, bl[n], acc_hl[n], 0, 0, 0);
#pragma unroll
        for (int n = 0; n < 4; ++n)
            acc_hl[n] = __builtin_amdgcn_mfma_f32_16x16x32_f16(al, bh[n], acc_hl[n], 0, 0, 0);
    }

    // epilogue: token = t0 + hi*4 + r, expert = n*16 + lo
    float* Lb = L + (size_t)(t0 + hi * 4) * NEXP + lo;
#pragma unroll
    for (int n = 0; n < 4; ++n) {
#pragma unroll
        for (int r = 0; r < 4; ++r) {
            Lb[(size_t)r * NEXP + n * 16] =
                acc_hh[n][r] + acc_hl[n][r] * (1.0f / 2048.0f);
        }
    }
}

// ---------------------------------------------------------------------------
// Kernel 2 (cooperative): sinkhorn + top-2 + softmax gather. UNCHANGED from
// the 302us baseline (isolating the GEMM change this round).
// Grid = 64 blocks x 1024 threads. Wave w (0..15) of block b owns tokens
// b*256 + w*16 .. +15; lane = expert. cost in registers.
// ---------------------------------------------------------------------------
__global__ __launch_bounds__(1024) void sinkhorn_router(const float* __restrict__ L,
                                                        float* __restrict__ colbuf,
                                                        float* __restrict__ out,
                                                        int nh) {
    cooperative_groups::grid_group grid = cooperative_groups::this_grid();

    __shared__ float part[16][64];
    __shared__ float redq[64][17];
    __shared__ float d1s[64];
    __shared__ float err_s;

    const int b     = blockIdx.x;   // 0..63
    const int tid   = (int)threadIdx.x;
    const int w     = tid >> 6;     // wave 0..15
    const int lane  = tid & 63;     // expert index
    const int tbase = b * 256 + w * 16;

    float logit[16], cost[16], dreg[16];
#pragma unroll
    for (int j = 0; j < 16; ++j) {
        const int t = tbase + j;
        float l = L[(size_t)t * NEXP + lane];
        for (int h = 1; h < nh; ++h)
            l += L[(size_t)h * NTOK * NEXP + (size_t)t * NEXP + lane];
        logit[j] = l;
        cost[j]  = expf(l);
        dreg[j]  = 0.0f;
    }

    float d1l   = 1.0f;   // this lane's d1[e]
    float d1old = 1.0f;   // previous d1 (used by tid<64 for err)
    int   g     = 0;

    for (;;) {
        // ---- phase A: d0 per token + per-wave column partials ----
        float colacc = 0.0f;
#pragma unroll
        for (int j = 0; j < 16; ++j) {
            float s = d1l * cost[j];
#pragma unroll
            for (int m = 32; m; m >>= 1) s += __shfl_xor(s, m, 64);
            const float d0 = (1.0f / 16384.0f) / (s + EPSF);
            dreg[j] = d0;
            colacc = fmaf(d0, cost[j], colacc);
        }
        part[w][lane] = colacc;
        __syncthreads();

        float* cb = colbuf + (size_t)(g & 1) * (NEXP * SBLK);
        if (tid < 64) {
            float s = part[0][tid];
#pragma unroll
            for (int q = 1; q < 16; ++q) s += part[q][tid];
            cb[tid * SBLK + b] = s;     // reader-coalesced layout [e][b]
        }
        grid.sync();

        // ---- phase B: cross-block column reduction, all 1024 threads ----
        {
            const int e = tid >> 4;     // 0..63
            const int q = tid & 15;     // 0..15 -> blocks q*4..q*4+3
            const float4 v = *(const float4*)(cb + e * SBLK + q * 4);
            redq[e][q] = (v.x + v.y) + (v.z + v.w);
        }
        __syncthreads();

        if (tid < 64) {
            float tot = redq[tid][0];
#pragma unroll
            for (int q = 1; q < 16; ++q) tot += redq[tid][q];
            const float d1n = (1.0f / 64.0f) / (tot + EPSF);
            float diff = fabsf(d1old - d1n);
#pragma unroll
            for (int m = 32; m; m >>= 1) diff += __shfl_xor(diff, m, 64);
            d1s[tid] = d1n;
            d1old    = d1n;
            if (tid == 0) err_s = diff * (1.0f / 64.0f);
        }
        __syncthreads();
        d1l = d1s[lane];
        const float err = err_s;
        ++g;
        if (!(err > TOLF) || g >= 512) break;   // matches while(err>tol); NaN stops
    }

    // ---- final: per token top-2 of d1*cost*d0, softmax gather ----
#pragma unroll 1
    for (int j = 0; j < 16; ++j) {
        const int t = tbase + j;
        const float v = (d1l * cost[j]) * dreg[j];

        float bv = v; int bi = lane;
#pragma unroll
        for (int m = 32; m; m >>= 1) {
            const float ov = __shfl_xor(bv, m, 64);
            const int   oi = __shfl_xor(bi, m, 64);
            if (ov > bv || (ov == bv && oi < bi)) { bv = ov; bi = oi; }
        }
        const int i1 = bi;

        const float v2 = (lane == i1) ? -INFINITY : v;
        float bv2 = v2; int bi2 = lane;
#pragma unroll
        for (int m = 32; m; m >>= 1) {
            const float ov = __shfl_xor(bv2, m, 64);
            const int   oi = __shfl_xor(bi2, m, 64);
            if (ov > bv2 || (ov == bv2 && oi < bi2)) { bv2 = ov; bi2 = oi; }
        }
        const int i2 = bi2;

        float mx = logit[j];
#pragma unroll
        for (int m = 32; m; m >>= 1) mx = fmaxf(mx, __shfl_xor(mx, m, 64));
        const float e = expf(logit[j] - mx);
        float se = e;
#pragma unroll
        for (int m = 32; m; m >>= 1) se += __shfl_xor(se, m, 64);

        const float p1 = __shfl(e, i1, 64) / se;
        const float p2 = __shfl(e, i2, 64) / se;

        if (lane == 0) {
            out[(size_t)t * 2 + 0] = p1;
            out[(size_t)t * 2 + 1] = p2;
            out[(size_t)NTOK * 2 + (size_t)t * 2 + 0] = (float)i1;
            out[(size_t)NTOK * 2 + (size_t)t * 2 + 1] = (float)i2;
        }
    }
}

// ---------------------------------------------------------------------------
// ws layout (4.78 MB total, well under the proven-available 8.4 MB minimum):
//   [0,       256KB)  Wh f16 [64][2048]
//   [256KB,   512KB)  Wl f16 [64][2048] (pre-scaled x2048)
//   [512KB,   4.5MB)  L  f32 [16384][64]
//   [4.5MB,  +32KB )  colbuf (2 x 64 x 64 f32, sinkhorn ping-pong)
// ---------------------------------------------------------------------------
extern "C" void kernel_launch(void* const* d_in, const int* in_sizes, int n_in,
                              void* d_out, int out_size, void* d_ws, size_t ws_size,
                              hipStream_t stream) {
    const float* x = (const float*)d_in[0];
    const float* W = (const float*)d_in[1];
    float* out = (float*)d_out;

    _Float16* Wh = (_Float16*)d_ws;
    _Float16* Wl = Wh + (size_t)NEXP * HID;                  // +131072 elems
    float* L      = (float*)((char*)d_ws + 524288);
    float* colbuf = L + (size_t)NTOK * NEXP;

    convert_w<<<dim3(64), dim3(256), 0, stream>>>(W, Wh, Wl);
    gemm_mfma<<<dim3(256), dim3(256), 0, stream>>>(x, Wh, Wl, L);

    int nh = 1;
    void* args[] = { (void*)&L, (void*)&colbuf, (void*)&out, (void*)&nh };
    hipLaunchCooperativeKernel((void*)sinkhorn_router, dim3(SBLK), dim3(1024),
                               args, 0, stream);
}